// Round 10
// baseline (172.310 us; speedup 1.0000x reference)
//
#include <hip/hip_runtime.h>

#define B_SZ   32
#define T_LEN  160000
#define NFFT   1024
#define HOP    320
#define FRAMES 501
#define NBINS  513
#define PADL   512

#define XP_STRIDE 164864                  // padded per-batch xp length (elements)
#define WS_XP_OFF (1025 * NFFT)           // ushort-element offset of xp region in ws
#define XP_G8_PB  (XP_STRIDE / 8)         // 20608 8-elem groups per batch

// prep-kernel block ranges: [0,512) basis rows 0..1023 | 512: w512 row | xp convert
#define PB_BASIS  512
#define PB_XP     2576
#define PREP_BLOCKS (PB_BASIS + 1 + PB_XP)

// K-trim: Hann window (WIN=800) is zero outside k in [112,912) -> basis cols
// there are exactly 0.0. Cover with 64-aligned range [96,928): 13 tiles of 64.
#define KT0  96
#define NT64 13

typedef __bf16 bf16x8  __attribute__((ext_vector_type(8)));
typedef float  floatx4 __attribute__((ext_vector_type(4)));

__device__ __forceinline__ unsigned short f2bf(float f) {
    unsigned u = __builtin_bit_cast(unsigned, f);
    u += 0x7FFFu + ((u >> 16) & 1u);      // round-to-nearest-even
    return (unsigned short)(u >> 16);
}

__device__ __forceinline__ void gl_lds16(const void* g, void* l) {
    __builtin_amdgcn_global_load_lds(
        (const __attribute__((address_space(1))) unsigned int*)g,
        (__attribute__((address_space(3))) unsigned int*)l, 16, 0, 0);
}

// ---- prep: pure-bandwidth converts only (bin512 computed inside the GEMM) ----
__global__ void stft_prep(const float* __restrict__ x,
                          const float* __restrict__ basis,
                          unsigned short* __restrict__ basisb,
                          unsigned short* __restrict__ xpb,
                          float* __restrict__ out) {
    const int blk = blockIdx.x;
    const int tid = threadIdx.x;

    if (blk < PB_BASIS) {
        const int gid = blk * 256 + tid;          // 8 elems per thread, exact cover
        const int row = gid >> 7;                 // 0..1023
        const int col = (gid & 127) * 8;
        const int j = row >> 1, c = row & 1;
        const float* src = basis + (size_t)(j + c * NBINS) * NFFT + col;
        const float4 v0 = *(const float4*)(src);
        const float4 v1 = *(const float4*)(src + 4);
        ushort4 o0, o1;
        o0.x = f2bf(v0.x); o0.y = f2bf(v0.y); o0.z = f2bf(v0.z); o0.w = f2bf(v0.w);
        o1.x = f2bf(v1.x); o1.y = f2bf(v1.y); o1.z = f2bf(v1.z); o1.w = f2bf(v1.w);
        unsigned short* d = basisb + ((size_t)row << 10) + col;
        *(ushort4*)(d)     = o0;
        *(ushort4*)(d + 4) = o1;
    } else if (blk == PB_BASIS) {
        // w512 row: bf16 of basis row 512 (windowed cos_512); 256 thr x 4 elems
        const float4 v = *(const float4*)(basis + (size_t)512 * NFFT + tid * 4);
        ushort4 o;
        o.x = f2bf(v.x); o.y = f2bf(v.y); o.z = f2bf(v.z); o.w = f2bf(v.w);
        *(ushort4*)(basisb + ((size_t)1024 << 10) + tid * 4) = o;
    } else {
        const int i   = (blk - PB_BASIS - 1) * 256 + tid;   // 0..659455, exact cover
        const int b   = i / XP_G8_PB;
        const int pos = (i - b * XP_G8_PB) * 8;         // boundaries (512,160512) are %8==0
        ushort4 o0 = {0,0,0,0}, o1 = {0,0,0,0};
        if (pos >= PADL && pos < T_LEN + PADL) {
            const float* src = x + (size_t)b * T_LEN + (pos - PADL);
            const float4 v0 = *(const float4*)(src);
            const float4 v1 = *(const float4*)(src + 4);
            o0.x = f2bf(v0.x); o0.y = f2bf(v0.y); o0.z = f2bf(v0.z); o0.w = f2bf(v0.w);
            o1.x = f2bf(v1.x); o1.y = f2bf(v1.y); o1.z = f2bf(v1.z); o1.w = f2bf(v1.w);
        }
        unsigned short* d = xpb + (size_t)b * XP_STRIDE + pos;
        *(ushort4*)(d)     = o0;
        *(ushort4*)(d + 4) = o1;
    }
}

// ---- MFMA GEMM v10 = R2's deep pipeline with COMPILE-TIME buffer offsets
// (the R9 regression's cause was the runtime ro/so + single generic body),
// + K-trim (13 tiles of 64) + fused bin512 with the w512l read HOISTED into
// the pre-barrier frag-load region (covered by the existing lgkmcnt(0);
// register-carried into the kh's second phase -- no LDS wait inside the
// setprio/MFMA cluster, R9's other regression).
// 256x256 tile, 8 waves (2M x 4N -> 128x64/wave), BK=64 as 2x32 halves,
// 2 x 64KB LDS buffers, 4 phases per K-tile, counted vmcnt(8) (never 0
// in-loop), XOR-swizzled conflict-free LDS, grid batch-fastest (XCD = b%8,
// FETCH measured at compulsory 12.4MB).
// Loop: 6 iterations x 2 tiles (literal bufs 0/32768) + explicit tile-12
// epilogue (even -> ro=0). Ledger (re-derived for the odd tail): after
// tile-11-p4's vmcnt(8) the newest 8 are {A1(12),B1(12),A0(g),B0(g)} so
// A0/B0(12) are drained; tile-12-p2's vmcnt(8) drains A1/B1(12); the
// wrap-garbage stages (valid addrs, never read) drain at the final vmcnt(0).
__launch_bounds__(512, 2)
__global__ void stft_mfma_kernel(const unsigned short* __restrict__ basisb,
                                 const unsigned short* __restrict__ xpb,
                                 float* __restrict__ out) {
    __shared__ unsigned short lds[65536];    // 128 KB: 2 bufs x 4 parts x 8192
    __shared__ unsigned short w512l[1024];   // w512 row, global k in [0,1024)

    const int tid  = threadIdx.x;
    const int lane = tid & 63;
    const int w    = tid >> 6;        // wave 0..7
    const int wm   = w & 1;           // m-half of 256 (128 rows)
    const int wn   = w >> 1;          // n-quarter of 256 (64 frames)
    const int r0   = lane & 15;
    const int quad = lane >> 4;
    // swizzled 16B-slot within a 64-B row: slot = quad ^ ((row>>1)&3)
    const int ce   = (quad ^ ((r0 >> 1) & 3)) * 8;

    const int b   = blockIdx.x;                 // batch fastest -> XCD = b%8
    const int fg0 = blockIdx.y * 256;           // frame tile base (0,256)
    const int mg0 = blockIdx.z * 256;           // row tile base (0..768)
    const unsigned short* xpbb = xpb + (size_t)b * XP_STRIDE;
    const bool do512 = (mg0 == 0) && (wm == 0); // wave-uniform

    // staging: each half-tile (A or B, 256 rows x 32 k = 16 KB) = 2 issues/thread.
    // LDS dest linear; global source column pre-swizzled (same involution as reads).
    const int i0 = tid, i1 = 512 + tid;
    const int row0 = i0 >> 2, row1 = i1 >> 2;          // 0..127, 128..255
    const int cs0 = ((i0 & 3) ^ ((row0 >> 1) & 3)) * 8;
    const int cs1 = ((i1 & 3) ^ ((row1 >> 1) & 3)) * 8;
    const unsigned short* arow0 = basisb + ((size_t)(mg0 + row0) << 10) + cs0;
    const unsigned short* arow1 = basisb + ((size_t)(mg0 + row1) << 10) + cs1;
    const unsigned short* brow0 = xpbb + (size_t)(fg0 + row0) * HOP + cs0;
    const unsigned short* brow1 = xpbb + (size_t)(fg0 + row1) * HOP + cs1;

#define WRAP13(x) ((x) >= NT64 ? (x) - NT64 : (x))
#define STAGE_A(kt, kh, bo) do {                                    \
    const int ko_ = KT0 + (kt) * 64 + (kh) * 32;                    \
    gl_lds16(arow0 + ko_, &lds[(bo) + (kh) * 8192 + i0 * 8]);       \
    gl_lds16(arow1 + ko_, &lds[(bo) + (kh) * 8192 + i1 * 8]);       \
} while (0)
#define STAGE_B(kt, kh, bo) do {                                    \
    const int ko_ = KT0 + (kt) * 64 + (kh) * 32;                    \
    gl_lds16(brow0 + ko_, &lds[(bo) + (2 + (kh)) * 8192 + i0 * 8]); \
    gl_lds16(brow1 + ko_, &lds[(bo) + (2 + (kh)) * 8192 + i1 * 8]); \
} while (0)

    floatx4 acc[8][4] = {};
    floatx4 acc512[4] = {};
    bf16x8 af[8], bf[2];
    bf16x8 aw = {};                   // w512 slice; stays 0 for r0!=0 lanes

#define LOAD_A(kh, RO) do {                                                   \
    const unsigned short* pa_ =                                               \
        &lds[(RO) + (kh) * 8192 + (wm * 128 + r0) * 32 + ce];                 \
    _Pragma("unroll")                                                         \
    for (int mt = 0; mt < 8; ++mt) af[mt] = *(const bf16x8*)(pa_ + mt * 512); \
} while (0)
#define LOAD_B(kh, nh, RO) do {                                               \
    const unsigned short* pb_ =                                               \
        &lds[(RO) + (2 + (kh)) * 8192 + (wn * 64 + (nh) * 32 + r0) * 32 + ce];\
    bf[0] = *(const bf16x8*)(pb_);                                            \
    bf[1] = *(const bf16x8*)(pb_ + 512);                                      \
} while (0)
#define MFMA16(nh) do {                                                       \
    _Pragma("unroll")                                                         \
    for (int mt = 0; mt < 8; ++mt) {                                          \
        acc[mt][(nh) * 2]     = __builtin_amdgcn_mfma_f32_16x16x32_bf16(      \
            af[mt], bf[0], acc[mt][(nh) * 2], 0, 0, 0);                       \
        acc[mt][(nh) * 2 + 1] = __builtin_amdgcn_mfma_f32_16x16x32_bf16(      \
            af[mt], bf[1], acc[mt][(nh) * 2 + 1], 0, 0, 0);                   \
    }                                                                         \
} while (0)
#define VMC8 asm volatile("s_waitcnt vmcnt(8)" ::: "memory")
// phase: frag loads (+ hoisted aw read on each kh's first phase, covered by
// the lgkmcnt(0)) -> stage -> barrier -> lgkm(0) -> MFMA cluster -> vm -> barrier
#define PHASE(kh, nh, tt, RO, DO_STAGE, DO_VM) do {                           \
    if ((nh) == 0) {                                                          \
        LOAD_A(kh, RO);                                                       \
        if (do512 && r0 == 0)                                                 \
            aw = *(const bf16x8*)(&w512l[KT0 + (tt) * 64 + (kh) * 32 + quad * 8]); \
    }                                                                         \
    LOAD_B(kh, nh, RO);                                                       \
    DO_STAGE;                                                                 \
    __builtin_amdgcn_s_barrier();                                             \
    asm volatile("s_waitcnt lgkmcnt(0)" ::: "memory");                        \
    __builtin_amdgcn_s_setprio(1);                                            \
    MFMA16(nh);                                                               \
    if (do512) {                                  /* wave-uniform, reg-only */ \
        acc512[(nh) * 2]     = __builtin_amdgcn_mfma_f32_16x16x32_bf16(       \
            aw, bf[0], acc512[(nh) * 2], 0, 0, 0);                            \
        acc512[(nh) * 2 + 1] = __builtin_amdgcn_mfma_f32_16x16x32_bf16(       \
            aw, bf[1], acc512[(nh) * 2 + 1], 0, 0, 0);                        \
    }                                                                         \
    __builtin_amdgcn_s_setprio(0);                                            \
    DO_VM;                                                                    \
    __builtin_amdgcn_s_barrier();                                             \
} while (0)
// one K-tile: stage A1/B1(tt+1)->other buf in p1/p2, A0/B0(tt+2)->own buf in p3/p4
#define TILE(tt, RO, SO) do {                                                 \
    PHASE(0, 0, tt, RO, STAGE_A(WRAP13((tt) + 1), 1, SO), );                  \
    PHASE(0, 1, tt, RO, STAGE_B(WRAP13((tt) + 1), 1, SO), VMC8);              \
    PHASE(1, 0, tt, RO, STAGE_A(WRAP13((tt) + 2), 0, RO), );                  \
    PHASE(1, 1, tt, RO, STAGE_B(WRAP13((tt) + 2), 0, RO), VMC8);              \
} while (0)

    // prologue: w512 (2) then A0(0) B0(0) A1(0) B1(0) -> buf0, A0(1) B0(1) -> buf1
    // = 14 issues; vmcnt(8) drains the oldest 6 = w512 + A0(0) + B0(0).
    gl_lds16(basisb + ((size_t)1024 << 10) + lane * 8, &w512l[lane * 8]);
    gl_lds16(basisb + ((size_t)1024 << 10) + 512 + lane * 8, &w512l[512 + lane * 8]);
    STAGE_A(0, 0, 0); STAGE_B(0, 0, 0);
    STAGE_A(0, 1, 0); STAGE_B(0, 1, 0);
    STAGE_A(1, 0, 32768); STAGE_B(1, 0, 32768);
    VMC8;
    __builtin_amdgcn_s_barrier();

    #pragma unroll 1
    for (int t = 0; t < NT64 - 1; t += 2) {      // tiles 0..11, literal buf offsets
        TILE(t,     0,     32768);
        TILE(t + 1, 32768, 0);
    }
    TILE(12, 0, 32768);                          // odd tail; stages wrap garbage
    // drain wrap-around garbage LDS-DMA before LDS is freed
    asm volatile("s_waitcnt vmcnt(0)" ::: "memory");

    // epilogue: rows are interleaved (cos,sin) pairs -> coalesced float2 stores
    const int mb = mg0 + wm * 128 + quad * 4;     // even
    const int fb = fg0 + wn * 64 + r0;
    #pragma unroll
    for (int nt = 0; nt < 4; ++nt) {
        const int f = fb + nt * 16;
        if (f >= FRAMES) continue;
        #pragma unroll
        for (int mt = 0; mt < 8; ++mt) {
            const int mrow = mb + mt * 16;
            const floatx4 v = acc[mt][nt];
            #pragma unroll
            for (int p = 0; p < 2; ++p) {
                const int bin = (mrow + 2 * p) >> 1;
                float2 val;
                val.x = v[2 * p];      // cos
                val.y = v[2 * p + 1];  // sin
                *(float2*)(out + (((size_t)b * NBINS + bin) * FRAMES + f) * 2) = val;
            }
        }
    }
    // bin512: output row 0 lives in quad==0 lanes, reg 0, col=r0
    if (do512 && quad == 0) {
        #pragma unroll
        for (int nt = 0; nt < 4; ++nt) {
            const int f = fb + nt * 16;
            if (f < FRAMES) {
                float2 val; val.x = acc512[nt][0]; val.y = 0.f;
                *(float2*)(out + (((size_t)b * NBINS + 512) * FRAMES + f) * 2) = val;
            }
        }
    }
#undef WRAP13
#undef STAGE_A
#undef STAGE_B
#undef LOAD_A
#undef LOAD_B
#undef MFMA16
#undef VMC8
#undef PHASE
#undef TILE
}

extern "C" void kernel_launch(void* const* d_in, const int* in_sizes, int n_in,
                              void* d_out, int out_size, void* d_ws, size_t ws_size,
                              hipStream_t stream) {
    const float* x     = (const float*)d_in[0];
    const float* basis = (const float*)d_in[1];
    float* out         = (float*)d_out;

    unsigned short* basis_bf = (unsigned short*)d_ws;
    unsigned short* xp_bf    = (unsigned short*)d_ws + WS_XP_OFF;

    stft_prep<<<dim3(PREP_BLOCKS), dim3(256), 0, stream>>>(x, basis, basis_bf, xp_bf, out);

    // batch fastest -> XCD = b%8: per-XCD footprint = A 2MB + 4 batches' xp
    // 1.3MB < 4MB L2 (measured FETCH = compulsory 12.4MB).
    dim3 grid(B_SZ, 2, 4);   // 256 blocks (1/CU, 130KB LDS)
    stft_mfma_kernel<<<grid, dim3(512), 0, stream>>>(basis_bf, xp_bf, out);
}

// Round 11
// 117.607 us; speedup vs baseline: 1.4651x; 1.4651x over previous
//
#include <hip/hip_runtime.h>

#define B_SZ   32
#define T_LEN  160000
#define NFFT   1024
#define HOP    320
#define FRAMES 501
#define NBINS  513
#define PADL   512

#define XP_STRIDE 164864                  // padded per-batch xp length (elements)
#define WS_XP_OFF (1024 * NFFT)           // ushort-element offset of xp region in ws
#define XP_G8_PB  (XP_STRIDE / 8)         // 20608 8-elem groups per batch

// prep-kernel block ranges: [0,512) basis rows 0..1023 | xp convert
#define PB_BASIS  512
#define PB_XP     2576
#define PREP_BLOCKS (PB_BASIS + PB_XP)

// K-trim: Hann window (WIN=800) is zero outside k in [112,912) -> basis cols
// there are exactly 0.0. Cover with 64-aligned range [96,928): 13 tiles of 64.
#define KT0  96
#define NT64 13

typedef __bf16 bf16x8  __attribute__((ext_vector_type(8)));
typedef float  floatx4 __attribute__((ext_vector_type(4)));

__device__ __forceinline__ unsigned short f2bf(float f) {
    unsigned u = __builtin_bit_cast(unsigned, f);
    u += 0x7FFFu + ((u >> 16) & 1u);      // round-to-nearest-even
    return (unsigned short)(u >> 16);
}

__device__ __forceinline__ void gl_lds16(const void* g, void* l) {
    __builtin_amdgcn_global_load_lds(
        (const __attribute__((address_space(1))) unsigned int*)g,
        (__attribute__((address_space(3))) unsigned int*)l, 16, 0, 0);
}

// ---- prep: pure-bandwidth converts. ROW-1 SUBSTITUTION: basisb row 1 would
// be sin_0 == all zeros (its output, bin0.imag, is identically 0). We store
// w512 (windowed cos_512, the bin-512 real basis) there instead; the GEMM then
// computes bin512.real in row 1's slot for free, and the epilogue routes it.
__global__ void stft_prep(const float* __restrict__ x,
                          const float* __restrict__ basis,
                          unsigned short* __restrict__ basisb,
                          unsigned short* __restrict__ xpb,
                          float* __restrict__ out) {
    const int blk = blockIdx.x;
    const int tid = threadIdx.x;

    if (blk < PB_BASIS) {
        const int gid = blk * 256 + tid;          // 8 elems per thread, exact cover
        const int row = gid >> 7;                 // 0..1023
        const int col = (gid & 127) * 8;
        const int j = row >> 1, c = row & 1;
        // row 1 (sin_0, all zeros) is replaced by basis row 512 = w512
        const size_t srow = (row == 1) ? (size_t)512 : (size_t)(j + c * NBINS);
        const float* src = basis + srow * NFFT + col;
        const float4 v0 = *(const float4*)(src);
        const float4 v1 = *(const float4*)(src + 4);
        ushort4 o0, o1;
        o0.x = f2bf(v0.x); o0.y = f2bf(v0.y); o0.z = f2bf(v0.z); o0.w = f2bf(v0.w);
        o1.x = f2bf(v1.x); o1.y = f2bf(v1.y); o1.z = f2bf(v1.z); o1.w = f2bf(v1.w);
        unsigned short* d = basisb + ((size_t)row << 10) + col;
        *(ushort4*)(d)     = o0;
        *(ushort4*)(d + 4) = o1;
    } else {
        const int i   = (blk - PB_BASIS) * 256 + tid;   // 0..659455, exact cover
        const int b   = i / XP_G8_PB;
        const int pos = (i - b * XP_G8_PB) * 8;         // boundaries (512,160512) are %8==0
        ushort4 o0 = {0,0,0,0}, o1 = {0,0,0,0};
        if (pos >= PADL && pos < T_LEN + PADL) {
            const float* src = x + (size_t)b * T_LEN + (pos - PADL);
            const float4 v0 = *(const float4*)(src);
            const float4 v1 = *(const float4*)(src + 4);
            o0.x = f2bf(v0.x); o0.y = f2bf(v0.y); o0.z = f2bf(v0.z); o0.w = f2bf(v0.w);
            o1.x = f2bf(v1.x); o1.y = f2bf(v1.y); o1.z = f2bf(v1.z); o1.w = f2bf(v1.w);
        }
        unsigned short* d = xpb + (size_t)b * XP_STRIDE + pos;
        *(ushort4*)(d)     = o0;
        *(ushort4*)(d + 4) = o1;
    }
}

// ---- MFMA GEMM v11 = R2's proven deep pipeline, REGISTER-NEUTRAL bin512
// (row-1 substitution: no acc512 / aw / w512l -- the R10 spill cause) +
// K-trim (13 tiles of 64) with literal buffer offsets (the R9 slowdown cause).
// 256x256 tile, 8 waves (2M x 4N -> 128x64/wave), BK=64 as 2x32 halves,
// 2 x 64KB LDS buffers, 4 phases per K-tile, counted vmcnt(8) (never 0
// in-loop), XOR-swizzled conflict-free LDS, grid batch-fastest (XCD = b%8,
// FETCH measured at compulsory ~12.4MB).
// Loop: 6 iterations x 2 tiles (literal bufs 0/32768) + explicit tile-12 tail.
// Ledger (position-invariant, re-derived for the odd tail): tile 12's kh0 is
// staged by TILE(10) p3/p4 into buf0, its kh1 by TILE(11) p1/p2 into buf0;
// TILE(11) p3/p4 and TILE(12)'s stages write only wrap-garbage (valid addrs,
// never read), drained by the final vmcnt(0). Each vmcnt(8) drains the 4
// oldest issues = exactly the half-tile pair needed two phases later; every
// WAR overwrite lands >=1 barrier after the slot's last lgkm-drained read.
__launch_bounds__(512, 2)
__global__ void stft_mfma_kernel(const unsigned short* __restrict__ basisb,
                                 const unsigned short* __restrict__ xpb,
                                 float* __restrict__ out) {
    __shared__ unsigned short lds[65536];    // 128 KB: 2 bufs x 4 parts x 8192

    const int tid  = threadIdx.x;
    const int lane = tid & 63;
    const int w    = tid >> 6;        // wave 0..7
    const int wm   = w & 1;           // m-half of 256 (128 rows)
    const int wn   = w >> 1;          // n-quarter of 256 (64 frames)
    const int r0   = lane & 15;
    const int quad = lane >> 4;
    // swizzled 16B-slot within a 64-B row: slot = quad ^ ((row>>1)&3)
    const int ce   = (quad ^ ((r0 >> 1) & 3)) * 8;

    const int b   = blockIdx.x;                 // batch fastest -> XCD = b%8
    const int fg0 = blockIdx.y * 256;           // frame tile base (0,256)
    const int mg0 = blockIdx.z * 256;           // row tile base (0..768)
    const unsigned short* xpbb = xpb + (size_t)b * XP_STRIDE;

    // staging: each half-tile (A or B, 256 rows x 32 k = 16 KB) = 2 issues/thread.
    // LDS dest linear; global source column pre-swizzled (same involution as reads).
    const int i0 = tid, i1 = 512 + tid;
    const int row0 = i0 >> 2, row1 = i1 >> 2;          // 0..127, 128..255
    const int cs0 = ((i0 & 3) ^ ((row0 >> 1) & 3)) * 8;
    const int cs1 = ((i1 & 3) ^ ((row1 >> 1) & 3)) * 8;
    const unsigned short* arow0 = basisb + ((size_t)(mg0 + row0) << 10) + cs0;
    const unsigned short* arow1 = basisb + ((size_t)(mg0 + row1) << 10) + cs1;
    const unsigned short* brow0 = xpbb + (size_t)(fg0 + row0) * HOP + cs0;
    const unsigned short* brow1 = xpbb + (size_t)(fg0 + row1) * HOP + cs1;

#define WRAP13(x) ((x) >= NT64 ? (x) - NT64 : (x))
#define STAGE_A(kt, kh, bo) do {                                    \
    const int ko_ = KT0 + (kt) * 64 + (kh) * 32;                    \
    gl_lds16(arow0 + ko_, &lds[(bo) + (kh) * 8192 + i0 * 8]);       \
    gl_lds16(arow1 + ko_, &lds[(bo) + (kh) * 8192 + i1 * 8]);       \
} while (0)
#define STAGE_B(kt, kh, bo) do {                                    \
    const int ko_ = KT0 + (kt) * 64 + (kh) * 32;                    \
    gl_lds16(brow0 + ko_, &lds[(bo) + (2 + (kh)) * 8192 + i0 * 8]); \
    gl_lds16(brow1 + ko_, &lds[(bo) + (2 + (kh)) * 8192 + i1 * 8]); \
} while (0)

    floatx4 acc[8][4] = {};
    bf16x8 af[8], bf[2];

#define LOAD_A(kh, RO) do {                                                   \
    const unsigned short* pa_ =                                               \
        &lds[(RO) + (kh) * 8192 + (wm * 128 + r0) * 32 + ce];                 \
    _Pragma("unroll")                                                         \
    for (int mt = 0; mt < 8; ++mt) af[mt] = *(const bf16x8*)(pa_ + mt * 512); \
} while (0)
#define LOAD_B(kh, nh, RO) do {                                               \
    const unsigned short* pb_ =                                               \
        &lds[(RO) + (2 + (kh)) * 8192 + (wn * 64 + (nh) * 32 + r0) * 32 + ce];\
    bf[0] = *(const bf16x8*)(pb_);                                            \
    bf[1] = *(const bf16x8*)(pb_ + 512);                                      \
} while (0)
#define MFMA16(nh) do {                                                       \
    _Pragma("unroll")                                                         \
    for (int mt = 0; mt < 8; ++mt) {                                          \
        acc[mt][(nh) * 2]     = __builtin_amdgcn_mfma_f32_16x16x32_bf16(      \
            af[mt], bf[0], acc[mt][(nh) * 2], 0, 0, 0);                       \
        acc[mt][(nh) * 2 + 1] = __builtin_amdgcn_mfma_f32_16x16x32_bf16(      \
            af[mt], bf[1], acc[mt][(nh) * 2 + 1], 0, 0, 0);                   \
    }                                                                         \
} while (0)
#define VMC8 asm volatile("s_waitcnt vmcnt(8)" ::: "memory")
#define PHASE(kh, nh, RO, DO_STAGE, DO_VM) do {                               \
    if ((nh) == 0) { LOAD_A(kh, RO); }                                        \
    LOAD_B(kh, nh, RO);                                                       \
    DO_STAGE;                                                                 \
    __builtin_amdgcn_s_barrier();                                             \
    asm volatile("s_waitcnt lgkmcnt(0)" ::: "memory");                        \
    __builtin_amdgcn_s_setprio(1);                                            \
    MFMA16(nh);                                                               \
    __builtin_amdgcn_s_setprio(0);                                            \
    DO_VM;                                                                    \
    __builtin_amdgcn_s_barrier();                                             \
} while (0)
// one K-tile: stage A1/B1(tt+1)->other buf in p1/p2, A0/B0(tt+2)->own buf in p3/p4
#define TILE(tt, RO, SO) do {                                                 \
    PHASE(0, 0, RO, STAGE_A(WRAP13((tt) + 1), 1, SO), );                      \
    PHASE(0, 1, RO, STAGE_B(WRAP13((tt) + 1), 1, SO), VMC8);                  \
    PHASE(1, 0, RO, STAGE_A(WRAP13((tt) + 2), 0, RO), );                      \
    PHASE(1, 1, RO, STAGE_B(WRAP13((tt) + 2), 0, RO), VMC8);                  \
} while (0)

    // prologue: A0(0) B0(0) A1(0) B1(0) -> buf0, A0(1) B0(1) -> buf1 = 12
    // issues; vmcnt(8) drains the oldest 4 = A0(0)+B0(0).
    STAGE_A(0, 0, 0); STAGE_B(0, 0, 0);
    STAGE_A(0, 1, 0); STAGE_B(0, 1, 0);
    STAGE_A(1, 0, 32768); STAGE_B(1, 0, 32768);
    VMC8;
    __builtin_amdgcn_s_barrier();

    #pragma unroll 1
    for (int t = 0; t < NT64 - 1; t += 2) {      // tiles 0..11, literal buf offsets
        TILE(t,     0,     32768);
        TILE(t + 1, 32768, 0);
    }
    TILE(12, 0, 32768);                          // odd tail; stages wrap garbage
    // drain wrap-around garbage LDS-DMA before LDS is freed
    asm volatile("s_waitcnt vmcnt(0)" ::: "memory");

    // epilogue: rows are interleaved (cos,sin) pairs -> coalesced float2 stores.
    // Row-1 routing: rows (0,1) hold (cos_0, w512) -> write bin0 = (v[0], 0)
    // (bin0.imag is identically 0) and bin512 = (v[1], 0).
    const int mb = mg0 + wm * 128 + quad * 4;     // even
    const int fb = fg0 + wn * 64 + r0;
    #pragma unroll
    for (int nt = 0; nt < 4; ++nt) {
        const int f = fb + nt * 16;
        if (f >= FRAMES) continue;
        #pragma unroll
        for (int mt = 0; mt < 8; ++mt) {
            const int mrow = mb + mt * 16;
            const floatx4 v = acc[mt][nt];
            #pragma unroll
            for (int p = 0; p < 2; ++p) {
                const int bin = (mrow + 2 * p) >> 1;
                float2 val;
                if (mrow + 2 * p == 0) {          // rows (0,1): mg0==0,wm==0,quad==0,mt==0
                    val.x = v[0]; val.y = 0.f;    // bin 0: cos_0, imag==0 exactly
                    *(float2*)(out + (((size_t)b * NBINS + 0) * FRAMES + f) * 2) = val;
                    float2 v512; v512.x = v[1]; v512.y = 0.f;   // bin 512 from row 1
                    *(float2*)(out + (((size_t)b * NBINS + 512) * FRAMES + f) * 2) = v512;
                } else {
                    val.x = v[2 * p];      // cos
                    val.y = v[2 * p + 1];  // sin
                    *(float2*)(out + (((size_t)b * NBINS + bin) * FRAMES + f) * 2) = val;
                }
            }
        }
    }
#undef WRAP13
#undef STAGE_A
#undef STAGE_B
#undef LOAD_A
#undef LOAD_B
#undef MFMA16
#undef VMC8
#undef PHASE
#undef TILE
}

extern "C" void kernel_launch(void* const* d_in, const int* in_sizes, int n_in,
                              void* d_out, int out_size, void* d_ws, size_t ws_size,
                              hipStream_t stream) {
    const float* x     = (const float*)d_in[0];
    const float* basis = (const float*)d_in[1];
    float* out         = (float*)d_out;

    unsigned short* basis_bf = (unsigned short*)d_ws;
    unsigned short* xp_bf    = (unsigned short*)d_ws + WS_XP_OFF;

    stft_prep<<<dim3(PREP_BLOCKS), dim3(256), 0, stream>>>(x, basis, basis_bf, xp_bf, out);

    // batch fastest -> XCD = b%8: per-XCD footprint = A 2MB + 4 batches' xp
    // 1.3MB < 4MB L2 (measured FETCH = compulsory ~12.4MB).
    dim3 grid(B_SZ, 2, 4);   // 256 blocks (1/CU, 128KB LDS)
    stft_mfma_kernel<<<grid, dim3(512), 0, stream>>>(basis_bf, xp_bf, out);
}